// Round 1
// baseline (3280.146 us; speedup 1.0000x reference)
//
#include <hip/hip_runtime.h>
#include <cstdint>
#include <cstddef>

// Sinkhorn: B=64, N=M=1024, EPS=0.1, 50 iters.
// Non-log domain: K=exp(-C/eps) (bf16, stored in d_out's pi region; dead before
// final kernel overwrites it with pi). a=(mu+1e-8)/(K b); b=(nu+1e-8)/(K^T a).
// col pass writes NBLK partial sums per column; next kernel reduces them.

#define BB 64
#define NN 1024
#define MM 1024
#define NBLK 8
#define RPB 128  // rows per block (NN / NBLK)

__device__ __forceinline__ unsigned short f2bf(float f) {
  union { float f; unsigned int i; } u; u.f = f;
  unsigned int r = u.i + 0x7fffu + ((u.i >> 16) & 1u);  // RNE
  return (unsigned short)(r >> 16);
}

__global__ __launch_bounds__(256) void prep_kernel(const float* __restrict__ C,
                                                   unsigned short* __restrict__ K) {
  size_t idx = ((size_t)blockIdx.x * 256 + threadIdx.x) * 4;
  float4 c = *reinterpret_cast<const float4*>(C + idx);
  ushort4 k;
  k.x = f2bf(__expf(-10.f * c.x));
  k.y = f2bf(__expf(-10.f * c.y));
  k.z = f2bf(__expf(-10.f * c.z));
  k.w = f2bf(__expf(-10.f * c.w));
  *reinterpret_cast<ushort4*>(K + idx) = k;
}

// bpart init so that b_j = (nu_j+1e-8)/sum(bpart) == exp(v0/eps) = e^10
__global__ __launch_bounds__(256) void initb_kernel(const float* __restrict__ nu,
                                                    float* __restrict__ bpart) {
  int idx = blockIdx.x * 256 + threadIdx.x;  // < 64*8*1024
  int j = idx & 1023;
  int b = idx >> 13;
  bpart[idx] = (nu[(b << 10) + j] + 1e-8f) * 5.67499122e-6f;  // exp(-10)/8
}

// u-update: reduce bpart -> b, then a_i = (mu_i+1e-8) / sum_j K_ij b_j
__global__ __launch_bounds__(256) void row_kernel(const unsigned short* __restrict__ K,
                                                  const float* __restrict__ mu,
                                                  const float* __restrict__ nu,
                                                  const float* __restrict__ bpart,
                                                  float* __restrict__ a) {
  int b = blockIdx.x >> 3;
  int blk = blockIdx.x & 7;
  int r0 = blk * RPB;
  __shared__ __align__(16) float bl[MM];
  int tid = threadIdx.x;
  for (int j = tid; j < MM; j += 256) {
    float s = 0.f;
#pragma unroll
    for (int p = 0; p < NBLK; ++p) s += bpart[((b * NBLK + p) << 10) + j];
    bl[j] = (nu[(b << 10) + j] + 1e-8f) / s;
  }
  __syncthreads();
  int lane = tid & 63, wave = tid >> 6;
  // hoist this lane's 16 b values (cols c*256 + lane*4 + m) to registers
  float breg[4][4];
#pragma unroll
  for (int c = 0; c < 4; ++c) {
    float4 v = reinterpret_cast<const float4*>(bl + c * 256)[lane];
    breg[c][0] = v.x; breg[c][1] = v.y; breg[c][2] = v.z; breg[c][3] = v.w;
  }
  const unsigned short* Kb = K + ((size_t)b << 20);
#pragma unroll 2
  for (int rr = wave; rr < RPB; rr += 4) {
    int row = r0 + rr;
    const unsigned short* Kr = Kb + ((size_t)row << 10);
    float acc = 0.f;
#pragma unroll
    for (int c = 0; c < 4; ++c) {
      uint2 kk = *reinterpret_cast<const uint2*>(Kr + c * 256 + lane * 4);
      union { unsigned int i; float f; } t0, t1, t2, t3;
      t0.i = kk.x << 16; t1.i = kk.x & 0xffff0000u;
      t2.i = kk.y << 16; t3.i = kk.y & 0xffff0000u;
      acc += t0.f * breg[c][0] + t1.f * breg[c][1] + t2.f * breg[c][2] + t3.f * breg[c][3];
    }
#pragma unroll
    for (int off = 32; off; off >>= 1) acc += __shfl_xor(acc, off, 64);
    if (lane == 0) a[(b << 10) + row] = (mu[(b << 10) + row] + 1e-8f) / acc;
  }
}

// v-update partials: bpart[b][blk][j] = sum_{i in block} K_ij a_i
__global__ __launch_bounds__(256) void col_kernel(const unsigned short* __restrict__ K,
                                                  const float* __restrict__ a,
                                                  float* __restrict__ bpart) {
  int b = blockIdx.x >> 3;
  int blk = blockIdx.x & 7;
  int r0 = blk * RPB;
  __shared__ float al[RPB];
  int tid = threadIdx.x;
  if (tid < RPB) al[tid] = a[(b << 10) + r0 + tid];
  __syncthreads();
  const unsigned short* Kb = K + ((size_t)b << 20) + ((size_t)r0 << 10);
  float acc0 = 0.f, acc1 = 0.f, acc2 = 0.f, acc3 = 0.f;
#pragma unroll 4
  for (int i = 0; i < RPB; ++i) {
    float av = al[i];
    uint2 kk = *reinterpret_cast<const uint2*>(Kb + ((size_t)i << 10) + tid * 4);
    union { unsigned int i; float f; } t0, t1, t2, t3;
    t0.i = kk.x << 16; t1.i = kk.x & 0xffff0000u;
    t2.i = kk.y << 16; t3.i = kk.y & 0xffff0000u;
    acc0 += av * t0.f; acc1 += av * t1.f; acc2 += av * t2.f; acc3 += av * t3.f;
  }
  float4 o = {acc0, acc1, acc2, acc3};
  reinterpret_cast<float4*>(bpart + ((b * NBLK + blk) << 10))[tid] = o;
}

// pi = a_i * exp(-10*C) * b_j (exact exp from fp32 C); cost_b += sum(pi*C)
__global__ __launch_bounds__(256) void final_kernel(const float* __restrict__ C,
                                                    const float* __restrict__ a,
                                                    const float* __restrict__ nu,
                                                    const float* __restrict__ bpart,
                                                    float* __restrict__ cost,
                                                    float* __restrict__ pi) {
  int b = blockIdx.x >> 3;
  int blk = blockIdx.x & 7;
  int r0 = blk * RPB;
  __shared__ __align__(16) float bl[MM];
  int tid = threadIdx.x;
  for (int j = tid; j < MM; j += 256) {
    float s = 0.f;
#pragma unroll
    for (int p = 0; p < NBLK; ++p) s += bpart[((b * NBLK + p) << 10) + j];
    bl[j] = (nu[(b << 10) + j] + 1e-8f) / s;
  }
  __syncthreads();
  int j0 = tid * 4;
  float b0 = bl[j0], b1 = bl[j0 + 1], b2 = bl[j0 + 2], b3 = bl[j0 + 3];
  float csum = 0.f;
  const size_t base = ((size_t)b << 20) + ((size_t)r0 << 10);
  for (int rr = 0; rr < RPB; ++rr) {
    float av = a[(b << 10) + r0 + rr];
    const size_t off = base + ((size_t)rr << 10) + j0;
    float4 c4 = *reinterpret_cast<const float4*>(C + off);
    float p0 = av * b0 * expf(-10.f * c4.x);
    float p1 = av * b1 * expf(-10.f * c4.y);
    float p2 = av * b2 * expf(-10.f * c4.z);
    float p3 = av * b3 * expf(-10.f * c4.w);
    float4 o = {p0, p1, p2, p3};
    *reinterpret_cast<float4*>(pi + off) = o;
    csum += p0 * c4.x + p1 * c4.y + p2 * c4.z + p3 * c4.w;
  }
#pragma unroll
  for (int off = 32; off; off >>= 1) csum += __shfl_xor(csum, off, 64);
  __shared__ float wsum[4];
  if ((tid & 63) == 0) wsum[tid >> 6] = csum;
  __syncthreads();
  if (tid == 0) atomicAdd(cost + b, wsum[0] + wsum[1] + wsum[2] + wsum[3]);
}

extern "C" void kernel_launch(void* const* d_in, const int* in_sizes, int n_in,
                              void* d_out, int out_size, void* d_ws, size_t ws_size,
                              hipStream_t stream) {
  const float* mu = (const float*)d_in[0];
  const float* nu = (const float*)d_in[1];
  const float* C  = (const float*)d_in[2];
  float* out = (float*)d_out;
  float* cost = out;          // [64]
  float* pi = out + 64;       // [64*1024*1024]
  // K (bf16, 128MB) lives in the pi region: dead before final_kernel writes pi.
  unsigned short* K = (unsigned short*)pi;
  // small scratch in d_ws: a (256KB) + bpart (2MB) = 2.25MB
  float* a = (float*)d_ws;
  float* bpart = a + BB * NN;

  prep_kernel<<<65536, 256, 0, stream>>>(C, K);
  initb_kernel<<<2048, 256, 0, stream>>>(nu, bpart);
  for (int it = 0; it < 50; ++it) {
    row_kernel<<<512, 256, 0, stream>>>(K, mu, nu, bpart, a);
    col_kernel<<<512, 256, 0, stream>>>(K, a, bpart);
  }
  hipMemsetAsync(cost, 0, 64 * sizeof(float), stream);
  final_kernel<<<512, 256, 0, stream>>>(C, a, nu, bpart, cost, pi);
}